// Round 15
// baseline (200.451 us; speedup 1.0000x reference)
//
#include <hip/hip_runtime.h>
#include <stdint.h>

typedef int v4i __attribute__((ext_vector_type(4)));

#define EPS_F32 1.1920928955078125e-07f   // np.finfo(float32).eps = 2^-23

// ---------------------------------------------------------------------------
// Fused quant kernel: blocks [0,M) do per-token X quant, blocks [M,M+DOUT)
// do per-out-channel W quant.
// ---------------------------------------------------------------------------
__global__ __launch_bounds__(256) void quant_kernel(
    const float* __restrict__ X, const float* __restrict__ W,
    const float* __restrict__ ss,
    int8_t* __restrict__ Xq, float* __restrict__ xs,
    int8_t* __restrict__ Wq, float* __restrict__ ws,
    int DIN, int M)
{
    const int bid = blockIdx.x;
    const int tid = threadIdx.x;
    const bool isX = bid < M;
    const float* row = isX ? X + (size_t)bid * DIN
                           : W + (size_t)(bid - M) * DIN;

    float4 v[4];
    float amax = 0.f;
#pragma unroll
    for (int c = 0; c < 4; ++c) {
        const int k = c * 1024 + tid * 4;
        float4 xv = *(const float4*)(row + k);
        float4 sv = *(const float4*)(ss + k);
        float4 q;
        if (isX) { q.x = xv.x / sv.x; q.y = xv.y / sv.y;
                   q.z = xv.z / sv.z; q.w = xv.w / sv.w; }
        else     { q.x = xv.x * sv.x; q.y = xv.y * sv.y;
                   q.z = xv.z * sv.z; q.w = xv.w * sv.w; }
        v[c] = q;
        amax = fmaxf(amax, fmaxf(fmaxf(fabsf(q.x), fabsf(q.y)),
                                 fmaxf(fabsf(q.z), fabsf(q.w))));
    }
    __shared__ float red[4];
    for (int off = 32; off; off >>= 1) amax = fmaxf(amax, __shfl_xor(amax, off));
    const int lane = tid & 63, w = tid >> 6;
    if (lane == 0) red[w] = amax;
    __syncthreads();
    amax = fmaxf(fmaxf(red[0], red[1]), fmaxf(red[2], red[3]));

    float scale, lo;
    if (isX) { scale = fmaxf(amax, 1e-5f) / 127.0f;      lo = -127.f; }
    else     { scale = fmaxf(amax / 127.5f, EPS_F32);    lo = -128.f; }
    if (tid == 0) { if (isX) xs[bid] = scale; else ws[bid - M] = scale; }

    int* qout = isX ? (int*)(Xq + (size_t)bid * DIN)
                    : (int*)(Wq + (size_t)(bid - M) * DIN);
#pragma unroll
    for (int c = 0; c < 4; ++c) {
        float4 q = v[c];
        int b0 = (int)fminf(fmaxf(rintf(q.x / scale), lo), 127.f);
        int b1 = (int)fminf(fmaxf(rintf(q.y / scale), lo), 127.f);
        int b2 = (int)fminf(fmaxf(rintf(q.z / scale), lo), 127.f);
        int b3 = (int)fminf(fmaxf(rintf(q.w / scale), lo), 127.f);
        qout[c * 256 + tid] = (b0 & 255) | ((b1 & 255) << 8) |
                              ((b2 & 255) << 16) | ((b3 & 255) << 24);
    }
}

// ---------------------------------------------------------------------------
// int8 NT GEMM, 128x128 tiles, BKB=128, 4 waves (2x2 grid, 256 thr),
// 64 KiB dbuf LDS -> TWO blocks per CU.  mfma_i32_16x16x64_i8.
//
// ROUND 15 rationale: 7 intra-block schedule variants all hit the same
// serial floor (LDS-burst + MFMA-burst, ~132us) because 8 barrier-locked
// waves storm each pipe in lockstep.  This round changes the RESOURCE
// geometry instead:
//  * 2x2 wave grid: LDS read amplification A x2 + B x2 (vs x4/x2 at 2x4)
//    -> 128 KB reads per 16.8M ops (was 192 KB).
//  * 64 KB LDS/block -> 2 co-resident blocks per CU with INDEPENDENT
//    barrier clocks: one block's LDS phase overlaps the other's MFMA
//    phase (m114 co-scheduling), which no intra-block reorder achieved.
// Per-CU demand per 16.8M ops: LDS ~2250cy < MFMA 2613cy -> MFMA-bound
// if cross-block overlap materializes.
//
// Sync skeleton per kt = r7 (proven, replay-validated): {8 stage calls ->
// buf^1} {32 MFMA} {vmcnt(0); s_barrier} {16 frag reads from buf^1}.
// vmcnt(0) has no counted-N edge cases; last kt skips stage/reads.
// Swizzle: phys chunk = logical ^ (row&7), both sides; frag rows are
// base + (lane&15) with base % 8 == 0 -> read XOR term (lane&7), and
// staging rows rowStart + (tid>>3) with rowStart % 32 == 0 -> source
// chunk (tid&7)^((tid>>3)&7).  Identical algebra to the passing 256².
// ---------------------------------------------------------------------------
#define BM 128
#define BN 128
#define BKB 128

#define MFMA __builtin_amdgcn_mfma_i32_16x16x64_i8

__global__ __launch_bounds__(256, 2) void gemm_i8_kernel(
    const int8_t* __restrict__ Xq, const int8_t* __restrict__ Wq,
    const float* __restrict__ xs, const float* __restrict__ ws,
    const float* __restrict__ bias, float* __restrict__ Y,
    int M, int N, int K)
{
    __shared__ __align__(16) int8_t smem[65536];   // 2 x (A 16K + B 16K)

    const int tid  = threadIdx.x;
    const int lane = tid & 63;
    const int w    = tid >> 6;
    const int wr   = w >> 1, wc = w & 1;           // 2x2 wave grid

    // 2048 blocks; bijective XCD map: each XCD owns a 16x16 rect of the
    // 64x32 tile grid.
    const int bid = blockIdx.x;
    const int xcd = bid & 7, idx = bid >> 3;       // idx in [0,256)
    const int bm  = (xcd >> 1) * 16 + (idx >> 4);  // [0,64)
    const int bn  = (xcd & 1) * 16 + (idx & 15);   // [0,32)

    const int chnk0 = ((lane >> 4) ^ (lane & 7)) << 4;  // frag read, k-slice 0
    const int chnk1 = chnk0 ^ 64;                       // k-slice 1
    const int aRB = ((wr << 6) + (lane & 15)) << 7;     // A frag row-byte base
    const int bRB = ((wc << 6) + (lane & 15)) << 7;     // B frag row-byte base

    // staging: 256 threads cover 32 rows x 128 B per call; LDS dest is
    // wave-uniform base + lane*16; source pre-swizzled (both-sides rule).
    auto STAGE = [&](const int8_t* gtile, int region, int rowStart) {
        const int row = rowStart + (tid >> 3);
        const int8_t* src = gtile + (size_t)row * K
                          + (((tid & 7) ^ ((tid >> 3) & 7)) << 4);
        __builtin_amdgcn_global_load_lds(
            (const __attribute__((address_space(1))) void*)src,
            (__attribute__((address_space(3))) void*)(smem + region + ((rowStart + (w << 3)) << 7)),
            16, 0, 0);
    };

    v4i acc[4][4] = {};
    v4i aF[4][2], bF[4][2];

    const int KT = K / BKB;   // 32
    const int8_t* aT = Xq + (size_t)bm * BM * K;
    const int8_t* bT = Wq + (size_t)bn * BN * K;
    const int rowb = (lane >> 4) << 2;
    const int col  = lane & 15;

    // prologue: stage kt0 into buf0; read its fragments
    {
        STAGE(aT, 0, 0);      STAGE(aT, 0, 32);
        STAGE(aT, 0, 64);     STAGE(aT, 0, 96);
        STAGE(bT, 16384, 0);  STAGE(bT, 16384, 32);
        STAGE(bT, 16384, 64); STAGE(bT, 16384, 96);
        asm volatile("s_waitcnt vmcnt(0)" ::: "memory");
        __builtin_amdgcn_s_barrier();
#pragma unroll
        for (int i = 0; i < 4; ++i) {
            aF[i][0] = *(const v4i*)(smem + aRB + i * 2048 + chnk0);
            aF[i][1] = *(const v4i*)(smem + aRB + i * 2048 + chnk1);
        }
#pragma unroll
        for (int j = 0; j < 4; ++j) {
            bF[j][0] = *(const v4i*)(smem + 16384 + bRB + j * 2048 + chnk0);
            bF[j][1] = *(const v4i*)(smem + 16384 + bRB + j * 2048 + chnk1);
        }
    }

    for (int kt = 0; kt < KT; ++kt) {
        const int nAb = ((kt & 1) ^ 1) * 32768;
        const bool pf = (kt + 1 < KT);
        const int8_t* aTn = aT + (size_t)(kt + 1) * BKB;
        const int8_t* bTn = bT + (size_t)(kt + 1) * BKB;

        // ---- stage next tile into buf^1
        if (pf) {
            STAGE(aTn, nAb, 0);          STAGE(aTn, nAb, 32);
            STAGE(aTn, nAb, 64);         STAGE(aTn, nAb, 96);
            STAGE(bTn, nAb + 16384, 0);  STAGE(bTn, nAb + 16384, 32);
            STAGE(bTn, nAb + 16384, 64); STAGE(bTn, nAb + 16384, 96);
        }

        // ---- 32 MFMA on current fragments
        __builtin_amdgcn_s_setprio(1);
#pragma unroll
        for (int i = 0; i < 4; ++i)
#pragma unroll
            for (int j = 0; j < 4; ++j) {
                acc[i][j] = MFMA(aF[i][0], bF[j][0], acc[i][j], 0, 0, 0);
                acc[i][j] = MFMA(aF[i][1], bF[j][1], acc[i][j], 0, 0, 0);
            }
        __builtin_amdgcn_s_setprio(0);

        // ---- per-kt sync: stages landed, buffer published
        asm volatile("s_waitcnt vmcnt(0)" ::: "memory");
        __builtin_amdgcn_s_barrier();

        // ---- read next fragments from buf^1
        if (pf) {
#pragma unroll
            for (int i = 0; i < 4; ++i) {
                aF[i][0] = *(const v4i*)(smem + nAb + aRB + i * 2048 + chnk0);
                aF[i][1] = *(const v4i*)(smem + nAb + aRB + i * 2048 + chnk1);
            }
#pragma unroll
            for (int j = 0; j < 4; ++j) {
                bF[j][0] = *(const v4i*)(smem + nAb + 16384 + bRB + j * 2048 + chnk0);
                bF[j][1] = *(const v4i*)(smem + nAb + 16384 + bRB + j * 2048 + chnk1);
            }
        }
    }

    // ---- epilogue: dequant + bias (C/D layout col=lane&15, row=(lane>>4)*4+reg)
    {
        float wsv[4], bv[4];
#pragma unroll
        for (int j = 0; j < 4; ++j) {
            const int n = bn * BN + (wc << 6) + (j << 4) + col;
            wsv[j] = ws[n];
            bv[j]  = bias[n];
        }
#pragma unroll
        for (int i = 0; i < 4; ++i) {
            const int mbase = bm * BM + (wr << 6) + (i << 4) + rowb;
#pragma unroll
            for (int r = 0; r < 4; ++r) {
                const int m = mbase + r;
                const float xsm = xs[m];
                float* yrow = Y + (size_t)m * N;
#pragma unroll
                for (int j = 0; j < 4; ++j) {
                    const int n = bn * BN + (wc << 6) + (j << 4) + col;
                    yrow[n] = (float)acc[i][j][r] * xsm * wsv[j] + bv[j];
                }
            }
        }
    }
}

// ---------------------------------------------------------------------------
extern "C" void kernel_launch(void* const* d_in, const int* in_sizes, int n_in,
                              void* d_out, int out_size, void* d_ws, size_t ws_size,
                              hipStream_t stream) {
    const float* X    = (const float*)d_in[0];
    const float* W    = (const float*)d_in[1];
    const float* bias = (const float*)d_in[2];
    const float* ss   = (const float*)d_in[3];

    const int DIN  = in_sizes[3];              // 4096
    const int DOUT = in_sizes[2];              // 4096
    const int M    = in_sizes[0] / DIN;        // 8192

    int8_t* Xq = (int8_t*)d_ws;
    int8_t* Wq = Xq + (size_t)M * DIN;
    float*  xs = (float*)(Wq + (size_t)DOUT * DIN);
    float*  ws = xs + M;
    float*  Y  = (float*)d_out;

    quant_kernel<<<M + DOUT, 256, 0, stream>>>(X, W, ss, Xq, xs, Wq, ws, DIN, M);
    gemm_i8_kernel<<<(M / BM) * (DOUT / BN), 256, 0, stream>>>(Xq, Wq, xs, ws, bias, Y, M, DOUT, DIN);
}

// Round 16
// 173.077 us; speedup vs baseline: 1.1582x; 1.1582x over previous
//
#include <hip/hip_runtime.h>
#include <stdint.h>

typedef int v4i __attribute__((ext_vector_type(4)));

#define EPS_F32 1.1920928955078125e-07f   // np.finfo(float32).eps = 2^-23

// ---------------------------------------------------------------------------
// rss kernel: rss[k] = 1/ss[k] (exact IEEE div, once) so the X-quant path
// becomes a pure multiply.  ss > 0 always (ratio of positive absmaxes).
// ---------------------------------------------------------------------------
__global__ __launch_bounds__(256) void rss_kernel(
    const float* __restrict__ ss, float* __restrict__ rss, int DIN)
{
    const int i = blockIdx.x * 256 + threadIdx.x;
    if (i < DIN) rss[i] = 1.0f / ss[i];
}

// ---------------------------------------------------------------------------
// Fused quant kernel: blocks [0,M) per-token X quant (multiply by rss),
// blocks [M,M+DOUT) per-out-channel W quant (multiply by ss).  Both paths
// are now the same branchless q = v*s; the only division left is the one
// rscale = 1/scale per thread.  (Was ~32 div-sequences/thread ≈ 7 µs VALU.)
// ---------------------------------------------------------------------------
__global__ __launch_bounds__(256) void quant_kernel(
    const float* __restrict__ X, const float* __restrict__ W,
    const float* __restrict__ ss, const float* __restrict__ rss,
    int8_t* __restrict__ Xq, float* __restrict__ xs,
    int8_t* __restrict__ Wq, float* __restrict__ ws,
    int DIN, int M)
{
    const int bid = blockIdx.x;
    const int tid = threadIdx.x;
    const bool isX = bid < M;
    const float* row  = isX ? X + (size_t)bid * DIN
                            : W + (size_t)(bid - M) * DIN;
    const float* svec = isX ? rss : ss;

    float4 v[4];
    float amax = 0.f;
#pragma unroll
    for (int c = 0; c < 4; ++c) {
        const int k = c * 1024 + tid * 4;
        float4 xv = *(const float4*)(row + k);
        float4 sv = *(const float4*)(svec + k);
        float4 q;
        q.x = xv.x * sv.x; q.y = xv.y * sv.y;
        q.z = xv.z * sv.z; q.w = xv.w * sv.w;
        v[c] = q;
        amax = fmaxf(amax, fmaxf(fmaxf(fabsf(q.x), fabsf(q.y)),
                                 fmaxf(fabsf(q.z), fabsf(q.w))));
    }
    __shared__ float red[4];
    for (int off = 32; off; off >>= 1) amax = fmaxf(amax, __shfl_xor(amax, off));
    const int lane = tid & 63, w = tid >> 6;
    if (lane == 0) red[w] = amax;
    __syncthreads();
    amax = fmaxf(fmaxf(red[0], red[1]), fmaxf(red[2], red[3]));

    float scale, lo;
    if (isX) { scale = fmaxf(amax, 1e-5f) / 127.0f;      lo = -127.f; }
    else     { scale = fmaxf(amax / 127.5f, EPS_F32);    lo = -128.f; }
    if (tid == 0) { if (isX) xs[bid] = scale; else ws[bid - M] = scale; }
    const float rscale = 1.0f / scale;   // one exact div; then 16 muls

    int* qout = isX ? (int*)(Xq + (size_t)bid * DIN)
                    : (int*)(Wq + (size_t)(bid - M) * DIN);
#pragma unroll
    for (int c = 0; c < 4; ++c) {
        float4 q = v[c];
        int b0 = (int)fminf(fmaxf(rintf(q.x * rscale), lo), 127.f);
        int b1 = (int)fminf(fmaxf(rintf(q.y * rscale), lo), 127.f);
        int b2 = (int)fminf(fmaxf(rintf(q.z * rscale), lo), 127.f);
        int b3 = (int)fminf(fmaxf(rintf(q.w * rscale), lo), 127.f);
        qout[c * 256 + tid] = (b0 & 255) | ((b1 & 255) << 8) |
                              ((b2 & 255) << 16) | ((b3 & 255) << 24);
    }
}

// ---------------------------------------------------------------------------
// Persistent 2-tile int8 NT GEMM — BYTE-IDENTICAL to round 10 (best total,
// replay-validated).  256x256 tiles, BKB=128, 8 waves (2x4), 128 KiB dbuf
// LDS, mfma_i32_16x16x64_i8, grid 256 (1 block/CU), K-half sub-steps:
//   S0: 8 stages(next tile) + read fHI(cur) + MFMA(fLO)  -> vmcnt(0)+barrier
//   S1: read fLO(next buf)                  + MFMA(fHI)
// ---------------------------------------------------------------------------
#define BM 256
#define BN 256
#define BKB 128

#define MFMA __builtin_amdgcn_mfma_i32_16x16x64_i8

__global__ __launch_bounds__(512, 2) void gemm_i8_kernel(
    const int8_t* __restrict__ Xq, const int8_t* __restrict__ Wq,
    const float* __restrict__ xs, const float* __restrict__ ws,
    const float* __restrict__ bias, float* __restrict__ Y,
    int M, int N, int K)
{
    __shared__ __align__(16) int8_t smem[131072];

    const int tid  = threadIdx.x;
    const int lane = tid & 63;
    const int w    = tid >> 6;
    const int wrow = w >> 2, wcol = w & 3;

    const int bid    = blockIdx.x;
    const int xcd    = bid & 7, idx = bid >> 3;        // idx in [0,32)
    const int bmBase = (xcd >> 1) * 8 + (idx >> 3);    // seg0 bm; seg1 = +4
    const int bn     = (xcd & 1) * 8 + (idx & 7);

    const int srcSwz = ((lane & 7) ^ (lane >> 3)) << 4;  // staging source swizzle
    const int chnk0  = ((lane >> 4) ^ (lane & 7)) << 4;  // frag read, k-slice 0
    const int chnk1  = chnk0 ^ 64;                       // k-slice 1
    const int aRB = ((wrow << 6) + (lane & 15)) << 7;    // A frag row-byte base
    const int bRB = ((wcol << 5) + (lane & 15)) << 7;    // B frag row-byte base

    auto STAGE = [&](const int8_t* gtile, int region, int rowStart) {
        const int8_t* src = gtile +
            (size_t)(rowStart + (w << 3) + (lane >> 3)) * K + srcSwz;
        __builtin_amdgcn_global_load_lds(
            (const __attribute__((address_space(1))) void*)src,
            (__attribute__((address_space(3))) void*)(smem + region + ((rowStart + (w << 3)) << 7)),
            16, 0, 0);
    };

    v4i acc[8][4] = {};
    v4i fLA[8], fHA[8], fLB[4], fHB[4];   // K-half fragment sets (static names)

    const int KT = K / BKB;   // 32
    const int8_t* bT0 = Wq + (size_t)bn * BN * K;   // same B panel both segs
    const int rowb = (lane >> 4) << 2;
    const int col  = lane & 15;

    // prologue: stage tile (seg0,kt0) into buf0; read fLO from buf0
    {
        const int8_t* aT0 = Xq + (size_t)bmBase * BM * K;
        STAGE(aT0, 0,     0);   STAGE(aT0, 0,     64);
        STAGE(aT0, 0,     128); STAGE(aT0, 0,     192);
        STAGE(bT0, 32768, 0);   STAGE(bT0, 32768, 64);
        STAGE(bT0, 32768, 128); STAGE(bT0, 32768, 192);
        asm volatile("s_waitcnt vmcnt(0)" ::: "memory");
        __builtin_amdgcn_s_barrier();
#pragma unroll
        for (int i = 0; i < 4; ++i) {
            fLA[i]     = *(const v4i*)(smem + aRB + i * 2048 + chnk0);
            fLA[4 + i] = *(const v4i*)(smem + aRB + 16384 + i * 2048 + chnk0);
        }
#pragma unroll
        for (int j = 0; j < 2; ++j) {
            fLB[j]     = *(const v4i*)(smem + 32768 + bRB + j * 2048 + chnk0);
            fLB[2 + j] = *(const v4i*)(smem + 32768 + bRB + 16384 + j * 2048 + chnk0);
        }
    }

    for (int seg = 0; seg < 2; ++seg) {
        const int bm = bmBase + seg * 4;
        const int8_t* aT0 = Xq + (size_t)bm * BM * K;

        for (int kt = 0; kt < KT; ++kt) {
            const int Ab  = (kt & 1) * 65536;
            const int Bb  = Ab + 32768;
            const int nAb = ((kt & 1) ^ 1) * 65536;
            const int nBb = nAb + 32768;
            const bool more = (kt + 1 < KT);
            const bool pf   = more || (seg == 0);
            const int8_t* aTn = more ? aT0 + (size_t)(kt + 1) * BKB
                                     : Xq + (size_t)(bmBase + 4) * BM * K;
            const int8_t* bTn = more ? bT0 + (size_t)(kt + 1) * BKB : bT0;

            // ---- S0: 8 stages; read fHI(cur); MFMA on fLO (K 0..64)
            if (pf) { STAGE(aTn, nAb, 0);   STAGE(aTn, nAb, 64);
                      STAGE(aTn, nAb, 128); STAGE(aTn, nAb, 192);
                      STAGE(bTn, nBb, 0);   STAGE(bTn, nBb, 64);
                      STAGE(bTn, nBb, 128); STAGE(bTn, nBb, 192); }
#pragma unroll
            for (int i = 0; i < 4; ++i) {
                fHA[i]     = *(const v4i*)(smem + Ab + aRB + i * 2048 + chnk1);
                fHA[4 + i] = *(const v4i*)(smem + Ab + aRB + 16384 + i * 2048 + chnk1);
            }
#pragma unroll
            for (int j = 0; j < 2; ++j) {
                fHB[j]     = *(const v4i*)(smem + Bb + bRB + j * 2048 + chnk1);
                fHB[2 + j] = *(const v4i*)(smem + Bb + bRB + 16384 + j * 2048 + chnk1);
            }
            __builtin_amdgcn_s_setprio(1);
#pragma unroll
            for (int i = 0; i < 8; ++i)
#pragma unroll
                for (int j = 0; j < 4; ++j)
                    acc[i][j] = MFMA(fLA[i], fLB[j], acc[i][j], 0, 0, 0);
            __builtin_amdgcn_s_setprio(0);
            asm volatile("s_waitcnt vmcnt(0)" ::: "memory");  // all 8 stages landed
            __builtin_amdgcn_s_barrier();

            // ---- S1: read fLO(next buf); MFMA on fHI (K 64..128)
            if (pf) {
#pragma unroll
                for (int i = 0; i < 4; ++i) {
                    fLA[i]     = *(const v4i*)(smem + nAb + aRB + i * 2048 + chnk0);
                    fLA[4 + i] = *(const v4i*)(smem + nAb + aRB + 16384 + i * 2048 + chnk0);
                }
#pragma unroll
                for (int j = 0; j < 2; ++j) {
                    fLB[j]     = *(const v4i*)(smem + nBb + bRB + j * 2048 + chnk0);
                    fLB[2 + j] = *(const v4i*)(smem + nBb + bRB + 16384 + j * 2048 + chnk0);
                }
            }
            __builtin_amdgcn_s_setprio(1);
#pragma unroll
            for (int i = 0; i < 8; ++i)
#pragma unroll
                for (int j = 0; j < 4; ++j)
                    acc[i][j] = MFMA(fHA[i], fHB[j], acc[i][j], 0, 0, 0);
            __builtin_amdgcn_s_setprio(0);
        }

        // ----- epilogue: dequant + bias (layout col=lane&15, row=(lane>>4)*4+reg)
        {
            float wsv[4], bv[4];
#pragma unroll
            for (int j = 0; j < 4; ++j) {
                const int n = bn * BN + ((j >> 1) << 7) + (wcol << 5) + ((j & 1) << 4) + col;
                wsv[j] = ws[n];
                bv[j]  = bias[n];
            }
#pragma unroll
            for (int i = 0; i < 8; ++i) {
                const int mbase = bm * BM + ((i >> 2) << 7) + (wrow << 6) + ((i & 3) << 4) + rowb;
#pragma unroll
                for (int r = 0; r < 4; ++r) {
                    const int m = mbase + r;
                    const float xsm = xs[m];
                    float* yrow = Y + (size_t)m * N;
#pragma unroll
                    for (int j = 0; j < 4; ++j) {
                        const int n = bn * BN + ((j >> 1) << 7) + (wcol << 5) + ((j & 1) << 4) + col;
                        yrow[n] = (float)acc[i][j][r] * xsm * wsv[j] + bv[j];
                    }
                }
            }
        }

        if (seg == 0) {
#pragma unroll
            for (int i = 0; i < 8; ++i)
#pragma unroll
                for (int j = 0; j < 4; ++j)
                    acc[i][j] = (v4i){0, 0, 0, 0};
        }
    }
}

// ---------------------------------------------------------------------------
extern "C" void kernel_launch(void* const* d_in, const int* in_sizes, int n_in,
                              void* d_out, int out_size, void* d_ws, size_t ws_size,
                              hipStream_t stream) {
    const float* X    = (const float*)d_in[0];
    const float* W    = (const float*)d_in[1];
    const float* bias = (const float*)d_in[2];
    const float* ss   = (const float*)d_in[3];

    const int DIN  = in_sizes[3];              // 4096
    const int DOUT = in_sizes[2];              // 4096
    const int M    = in_sizes[0] / DIN;        // 8192

    int8_t* Xq  = (int8_t*)d_ws;
    int8_t* Wq  = Xq + (size_t)M * DIN;
    float*  xs  = (float*)(Wq + (size_t)DOUT * DIN);
    float*  ws  = xs + M;
    float*  rss = ws + DOUT;
    float*  Y   = (float*)d_out;

    rss_kernel<<<(DIN + 255) / 256, 256, 0, stream>>>(ss, rss, DIN);
    quant_kernel<<<M + DOUT, 256, 0, stream>>>(X, W, ss, rss, Xq, xs, Wq, ws, DIN, M);
    gemm_i8_kernel<<<(M / BM) * (DOUT / BN) / 2, 512, 0, stream>>>(Xq, Wq, xs, ws, bias, Y, M, DOUT, DIN);
}